// Round 8
// baseline (1205.700 us; speedup 1.0000x reference)
//
#include <hip/hip_runtime.h>
#include <hip/hip_bf16.h>

#define N_EDGES_C 1000000
#define EDGE_DIM_C 64
#define NODE_DIM_C 64
#define IN_DIM_C   192
#define HID_C      256
#define XPAD 200            // bf16 elems per X row (192+8 pad) -> 400B rows
#define HS_OFF 12800        // byte offset of swizzled H region (Xs = 32*400B)
#define T_TILES 10          // tiles (of 32 edges) per block; 31250/10 = 3125 blocks

typedef __attribute__((ext_vector_type(8))) short  short8;
typedef __attribute__((ext_vector_type(4))) float  f32x4;

// Workgroup barrier WITHOUT vmcnt drain (orders LDS only; stores/prefetch
// loads stay in flight across it -- T4).
#define BAR_LDS() asm volatile("s_waitcnt lgkmcnt(0)\n\ts_barrier" ::: "memory")

__device__ __forceinline__ unsigned short f2bf(float f) {
    union { float f; unsigned u; } v; v.f = f;
    unsigned u = v.u;
    u += 0x7fffu + ((u >> 16) & 1u);   // round-to-nearest-even
    return (unsigned short)(u >> 16);
}

// W1[192][256] -> W1T bf16 [256][192]; W2[256][256] -> W2T bf16 [256][256].
__global__ void prep_weights_kernel(const float* __restrict__ W1,
                                    const float* __restrict__ W2,
                                    unsigned short* __restrict__ W1T,
                                    unsigned short* __restrict__ W2T) {
    int tid = blockIdx.x * 256 + threadIdx.x;
    if (tid < IN_DIM_C * HID_C) {
        int n = tid / IN_DIM_C, k = tid - n * IN_DIM_C;
        W1T[tid] = f2bf(W1[k * HID_C + n]);
    } else {
        int t2 = tid - IN_DIM_C * HID_C;
        if (t2 < HID_C * HID_C) {
            int o = t2 / HID_C, k = t2 - o * HID_C;
            W2T[t2] = f2bf(W2[k * HID_C + o]);
        }
    }
}

// 256 threads = 4 waves; wave w owns feature slice [w*64, w*64+64) for both
// layers. Weights are STREAMED from L2 per kb (not reg-pinned): costs ~20TB/s
// of L2 reads but frees ~112 VGPR -> 3 independent blocks/CU (3 waves/SIMD,
// decorrelated barriers) instead of 1 lockstep block at 2 waves/SIMD.
// Tile = 32 edges, T_TILES per block, software-pipelined:
//   issueEV(t+1) [idx prefetched at t-1] | L1(t) | bar | write_lds(t+1)+epi1(t)
//   | bar | L2(t)+stores(t)
__global__ __launch_bounds__(256, 3) void edge_mlp_kernel(
    const float* __restrict__ E, const float* __restrict__ V,
    const int* __restrict__ srcI, const int* __restrict__ dstI,
    const unsigned short* __restrict__ W1T, const float* __restrict__ b1,
    const unsigned short* __restrict__ W2T, const float* __restrict__ b2,
    float* __restrict__ out)
{
    __shared__ unsigned char smem[HS_OFF + 16384];   // 29184 B
    unsigned short* Xs = (unsigned short*)smem;      // [32][XPAD] bf16

    const int tid = threadIdx.x;
    const int w  = tid >> 6;     // wave 0..3
    const int l  = tid & 63;
    const int lm = l & 15;
    const int lg = l >> 4;
    const int r0 = tid >> 4;     // staging row base 0..15
    const long block0 = (long)blockIdx.x * (32 * T_TILES);

    // ---- reg-staged next-tile data (lives across barriers) ----
    float4 fE[2];   // E rows: thread covers f4 f=tid+i*256 -> row f>>4, col f&15
    float4 fV[4];   // V gather rows r0, r0+16 (src), r0, r0+16 (dst)
    int idxN[4];    // prefetched gather indices for tile t+1

    auto load_idx = [&](long tb) {
        idxN[0] = srcI[tb + r0];
        idxN[1] = srcI[tb + r0 + 16];
        idxN[2] = dstI[tb + r0];
        idxN[3] = dstI[tb + r0 + 16];
    };

    // Issue E + V gather loads for tile at base tb, using idx[] for V rows.
    auto issueEV = [&](long tb, const int* idx) {
#pragma unroll
        for (int i = 0; i < 2; ++i) {
            int f = tid + i * 256;               // 0..511
            fE[i] = *reinterpret_cast<const float4*>(
                E + (size_t)(tb + (f >> 4)) * EDGE_DIM_C + (f & 15) * 4);
        }
#pragma unroll
        for (int i = 0; i < 4; ++i)
            fV[i] = *reinterpret_cast<const float4*>(
                V + (size_t)idx[i] * NODE_DIM_C + (tid & 15) * 4);
    };

    // Convert staged regs -> bf16, write Xs rows (X = [E | Vsrc | Vdst]).
    auto write_lds = [&]() {
#pragma unroll
        for (int i = 0; i < 2; ++i) {
            int f = tid + i * 256;
            ushort4 b;
            b.x = f2bf(fE[i].x); b.y = f2bf(fE[i].y);
            b.z = f2bf(fE[i].z); b.w = f2bf(fE[i].w);
            *reinterpret_cast<ushort4*>(
                &Xs[(f >> 4) * XPAD + (f & 15) * 4]) = b;
        }
#pragma unroll
        for (int i = 0; i < 4; ++i) {
            int r   = (i & 1) * 16 + r0;         // 0..31 within 32-edge tile
            int off = 64 + (i >> 1) * 64;        // 64: src half, 128: dst half
            ushort4 b;
            b.x = f2bf(fV[i].x); b.y = f2bf(fV[i].y);
            b.z = f2bf(fV[i].z); b.w = f2bf(fV[i].w);
            *reinterpret_cast<ushort4*>(
                &Xs[r * XPAD + off + (tid & 15) * 4]) = b;
        }
    };

    // ---- prologue: stage tile 0; prefetch idx(1) ----
    {
        int idx0[4];
        idx0[0] = srcI[block0 + r0];
        idx0[1] = srcI[block0 + r0 + 16];
        idx0[2] = dstI[block0 + r0];
        idx0[3] = dstI[block0 + r0 + 16];
        issueEV(block0, idx0);
        write_lds();
        if (T_TILES > 1) load_idx(block0 + 32);
    }
    BAR_LDS();

#pragma unroll 1
    for (int t = 0; t < T_TILES; ++t) {
        const long tb = block0 + (long)t * 32;
        int idxC[4];
        if (t + 1 < T_TILES) {
#pragma unroll
            for (int i = 0; i < 4; ++i) idxC[i] = idxN[i];
            issueEV(tb + 32, idxC);              // gathers fly under L1/epi
            if (t + 2 < T_TILES) load_idx(tb + 64);  // idx for next issue
        }

        // ---------------- Layer 1 (streamed W1 + LDS X) ----------------
        f32x4 acc[4][2];
#pragma unroll
        for (int a = 0; a < 4; ++a)
#pragma unroll
            for (int b = 0; b < 2; ++b)
                acc[a][b] = (f32x4){0.f, 0.f, 0.f, 0.f};

        const unsigned short* w1base = W1T + (size_t)(w * 64) * IN_DIM_C;
#pragma unroll
        for (int kb = 0; kb < 6; ++kb) {
            short8 aw[4], bx[2];
#pragma unroll
            for (int nt = 0; nt < 4; ++nt)
                aw[nt] = *reinterpret_cast<const short8*>(
                    w1base + (size_t)(nt * 16 + lm) * IN_DIM_C + kb * 32 + lg * 8);
#pragma unroll
            for (int mt = 0; mt < 2; ++mt)
                bx[mt] = *reinterpret_cast<const short8*>(
                    &Xs[(mt * 16 + lm) * XPAD + kb * 32 + lg * 8]);
#pragma unroll
            for (int nt = 0; nt < 4; ++nt)
#pragma unroll
                for (int mt = 0; mt < 2; ++mt)
                    acc[nt][mt] = __builtin_amdgcn_mfma_f32_16x16x32_bf16(
                        aw[nt], bx[mt], acc[nt][mt], 0, 0, 0);
        }
        BAR_LDS();                       // (1) all waves done reading Xs(t)

        if (t + 1 < T_TILES) write_lds();        // Xs(t+1)

        // epi1: +b1, relu, bf16 -> Hs (XOR-swizzled region at HS_OFF)
#pragma unroll
        for (int nt = 0; nt < 4; ++nt) {
            int n0 = w * 64 + nt * 16 + lg * 4;
            float4 bv = *reinterpret_cast<const float4*>(b1 + n0);
#pragma unroll
            for (int mt = 0; mt < 2; ++mt) {
                f32x4 a = acc[nt][mt];
                ushort4 hb;
                hb.x = f2bf(fmaxf(a[0] + bv.x, 0.f));
                hb.y = f2bf(fmaxf(a[1] + bv.y, 0.f));
                hb.z = f2bf(fmaxf(a[2] + bv.z, 0.f));
                hb.w = f2bf(fmaxf(a[3] + bv.w, 0.f));
                int m = mt * 16 + lm;
                int addr = m * 512 + ((n0 * 2) ^ (lm << 4));
                *reinterpret_cast<ushort4*>(smem + HS_OFF + addr) = hb;
            }
        }
        BAR_LDS();                       // (2) Xs(t+1) + Hs(t) ready

        // ---------------- Layer 2 (streamed W2 + LDS H) ----------------
#pragma unroll
        for (int a = 0; a < 4; ++a)
#pragma unroll
            for (int b = 0; b < 2; ++b)
                acc[a][b] = (f32x4){0.f, 0.f, 0.f, 0.f};

        const unsigned short* w2base = W2T + (size_t)(w * 64) * HID_C;
#pragma unroll
        for (int kb = 0; kb < 8; ++kb) {
            short8 aw[4], bh[2];
#pragma unroll
            for (int ot = 0; ot < 4; ++ot)
                aw[ot] = *reinterpret_cast<const short8*>(
                    w2base + (size_t)(ot * 16 + lm) * HID_C + kb * 32 + lg * 8);
#pragma unroll
            for (int mt = 0; mt < 2; ++mt) {
                int m = mt * 16 + lm;
                int addr = m * 512 + (((kb * 32 + lg * 8) * 2) ^ (lm << 4));
                bh[mt] = *reinterpret_cast<const short8*>(smem + HS_OFF + addr);
            }
#pragma unroll
            for (int ot = 0; ot < 4; ++ot)
#pragma unroll
                for (int mt = 0; mt < 2; ++mt)
                    acc[ot][mt] = __builtin_amdgcn_mfma_f32_16x16x32_bf16(
                        aw[ot], bh[mt], acc[ot][mt], 0, 0, 0);
        }

        // epi2: +b2, coalesced NT float4 store (never waited in-loop)
#pragma unroll
        for (int ot = 0; ot < 4; ++ot) {
            int o0 = w * 64 + ot * 16 + lg * 4;
            float4 bv = *reinterpret_cast<const float4*>(b2 + o0);
#pragma unroll
            for (int mt = 0; mt < 2; ++mt) {
                f32x4 a = acc[ot][mt];
                f32x4 r;
                r[0] = a[0] + bv.x;
                r[1] = a[1] + bv.y;
                r[2] = a[2] + bv.z;
                r[3] = a[3] + bv.w;
                __builtin_nontemporal_store(r, reinterpret_cast<f32x4*>(
                    out + (size_t)(tb + mt * 16 + lm) * HID_C + o0));
            }
        }
    }
}

extern "C" void kernel_launch(void* const* d_in, const int* in_sizes, int n_in,
                              void* d_out, int out_size, void* d_ws, size_t ws_size,
                              hipStream_t stream) {
    const float* E  = (const float*)d_in[0];
    const float* V  = (const float*)d_in[1];
    const int*   ei = (const int*)d_in[2];   // [2][N_EDGES] int32
    const float* W1 = (const float*)d_in[3];
    const float* b1 = (const float*)d_in[4];
    const float* W2 = (const float*)d_in[5];
    const float* b2 = (const float*)d_in[6];
    float* out = (float*)d_out;

    unsigned short* W1T = (unsigned short*)d_ws;                 // 256*192 bf16
    unsigned short* W2T = W1T + IN_DIM_C * HID_C;                // 256*256 bf16

    const int prep_total = IN_DIM_C * HID_C + HID_C * HID_C;     // 114688
    prep_weights_kernel<<<(prep_total + 255) / 256, 256, 0, stream>>>(W1, W2, W1T, W2T);

    const int nblocks = N_EDGES_C / (32 * T_TILES);              // 3125
    edge_mlp_kernel<<<nblocks, 256, 0, stream>>>(
        E, V, ei, ei + N_EDGES_C, W1T, b1, W2T, b2, out);
}

// Round 10
// 510.031 us; speedup vs baseline: 2.3640x; 2.3640x over previous
//
#include <hip/hip_runtime.h>
#include <hip/hip_bf16.h>

#define N_EDGES_C 1000000
#define EDGE_DIM_C 64
#define NODE_DIM_C 64
#define IN_DIM_C   192
#define HID_C      256
#define XPAD 200            // bf16 elems per X row (192+8 pad) -> 400B rows
#define XBUF_SZ 25600       // 64 rows * 400B
#define HS_OFF  51200       // H buffers start after 2 X buffers
#define HBUF_SZ 32768       // 64 rows * 512B (swizzled)
#define T_TILES 5           // tiles of 64 edges; 15625/5 = 3125 blocks

typedef __attribute__((ext_vector_type(8))) short  short8;
typedef __attribute__((ext_vector_type(4))) float  f32x4;

// Workgroup barrier WITHOUT vmcnt drain (orders LDS only; stores and
// not-yet-consumed prefetch loads stay in flight across it -- T4).
#define BAR_LDS() asm volatile("s_waitcnt lgkmcnt(0)\n\ts_barrier" ::: "memory")

__device__ __forceinline__ unsigned short f2bf(float f) {
    union { float f; unsigned u; } v; v.f = f;
    unsigned u = v.u;
    u += 0x7fffu + ((u >> 16) & 1u);   // round-to-nearest-even
    return (unsigned short)(u >> 16);
}

// W1[192][256] -> W1T bf16 [256][192]; W2[256][256] -> W2T bf16 [256][256].
__global__ void prep_weights_kernel(const float* __restrict__ W1,
                                    const float* __restrict__ W2,
                                    unsigned short* __restrict__ W1T,
                                    unsigned short* __restrict__ W2T) {
    int tid = blockIdx.x * 256 + threadIdx.x;
    if (tid < IN_DIM_C * HID_C) {
        int n = tid / IN_DIM_C, k = tid - n * IN_DIM_C;
        W1T[tid] = f2bf(W1[k * HID_C + n]);
    } else {
        int t2 = tid - IN_DIM_C * HID_C;
        if (t2 < HID_C * HID_C) {
            int o = t2 / HID_C, k = t2 - o * HID_C;
            W2T[t2] = f2bf(W2[k * HID_C + o]);
        }
    }
}

// 512 threads = 8 waves; wave w owns feature slice [w*32, w*32+32) for BOTH
// layers, W1/W2 fragments reg-pinned once per block (zero in-loop global
// loads besides prefetch gathers -- R8 proved streaming weights thrashes L2).
// Xs and Hs are DOUBLE-BUFFERED -> ONE lgkm-only barrier per tile:
//   issueEV(t+1) | L1(t) reads Xs[t&1] | epi1 -> Hs[t&1] |
//   write_lds(t+1) -> Xs[(t+1)&1] | BAR | L2(t) reads Hs[t&1] + NT stores
__global__ __launch_bounds__(512, 2) void edge_mlp_kernel(
    const float* __restrict__ E, const float* __restrict__ V,
    const int* __restrict__ srcI, const int* __restrict__ dstI,
    const unsigned short* __restrict__ W1T, const float* __restrict__ b1,
    const unsigned short* __restrict__ W2T, const float* __restrict__ b2,
    float* __restrict__ out)
{
    __shared__ unsigned char smem[HS_OFF + 2 * HBUF_SZ];   // 116736 B
    const int tid = threadIdx.x;
    const int w  = tid >> 6;     // wave 0..7
    const int l  = tid & 63;
    const int lm = l & 15;
    const int lg = l >> 4;
    const long block0 = (long)blockIdx.x * (64 * T_TILES);

    // ---- weight fragments -> registers (once per block) ----
    short8 wA1[6][2];            // [kb][nt]
    short8 wA2[8][2];            // [kb][ot]
#pragma unroll
    for (int kb = 0; kb < 6; ++kb)
#pragma unroll
        for (int nt = 0; nt < 2; ++nt)
            wA1[kb][nt] = *reinterpret_cast<const short8*>(
                W1T + (size_t)(w * 32 + nt * 16 + lm) * IN_DIM_C + kb * 32 + lg * 8);
#pragma unroll
    for (int kb = 0; kb < 8; ++kb)
#pragma unroll
        for (int ot = 0; ot < 2; ++ot)
            wA2[kb][ot] = *reinterpret_cast<const short8*>(
                W2T + (size_t)(w * 32 + ot * 16 + lm) * HID_C + kb * 32 + lg * 8);

    // ---- reg-staged next-tile data (lives across the barrier) ----
    f32x4 fE[2];   // wave's 8 E-rows x 64 f32
    f32x4 fV[4];   // wave's 8 (src,dst) V-rows

    const int kind = (l >> 3) & 1;               // 0:src 1:dst
    const int rr   = l & 7;
    const int* const ip = kind ? dstI : srcI;

    auto load_idx = [&](long tb) -> int {        // lanes 0-15: s0..7,d0..7
        return ip[tb + w * 8 + rr];
    };

    // Issue E + V gather loads for tile at base tb (idx prefetched earlier).
    auto issueEV = [&](long tb, int myidx) {
#pragma unroll
        for (int i = 0; i < 2; ++i) {
            int f = i * 64 + l;                  // row f>>4 in 0..7
            fE[i] = __builtin_nontemporal_load(reinterpret_cast<const f32x4*>(
                E + (size_t)(tb + w * 8 + (f >> 4)) * EDGE_DIM_C + (f & 15) * 4));
        }
#pragma unroll
        for (int i = 0; i < 4; ++i) {
            int kind2 = ((l & 31) < 16) ? 0 : 1; // src / dst half of X row
            int srcl  = kind2 * 8 + i * 2 + (l >> 5);
            int gi = __builtin_amdgcn_ds_bpermute(srcl << 2, myidx);
            fV[i] = *reinterpret_cast<const f32x4*>(
                V + (size_t)gi * NODE_DIM_C + (l & 15) * 4);
        }
    };

    // Convert staged regs -> bf16, write Xs[buf].
    auto write_lds = [&](int buf) {
        unsigned short* Xs = (unsigned short*)(smem + buf * XBUF_SZ);
#pragma unroll
        for (int i = 0; i < 2; ++i) {
            int f = i * 64 + l;
            ushort4 b;
            b.x = f2bf(fE[i][0]); b.y = f2bf(fE[i][1]);
            b.z = f2bf(fE[i][2]); b.w = f2bf(fE[i][3]);
            *reinterpret_cast<ushort4*>(
                &Xs[(w * 8 + (f >> 4)) * XPAD + (f & 15) * 4]) = b;
        }
#pragma unroll
        for (int i = 0; i < 4; ++i) {
            int kind2 = ((l & 31) < 16) ? 0 : 1;
            int rV    = i * 2 + (l >> 5);
            ushort4 b;
            b.x = f2bf(fV[i][0]); b.y = f2bf(fV[i][1]);
            b.z = f2bf(fV[i][2]); b.w = f2bf(fV[i][3]);
            *reinterpret_cast<ushort4*>(
                &Xs[(w * 8 + rV) * XPAD + 64 + kind2 * 64 + (l & 15) * 4]) = b;
        }
    };

    // ---- prologue: stage tile 0; prefetch idx for tile 1 ----
    {
        int idx0 = load_idx(block0);
        issueEV(block0, idx0);
        write_lds(0);
    }
    int idxNext = (T_TILES > 1) ? load_idx(block0 + 64) : 0;
    BAR_LDS();

#pragma unroll 1
    for (int t = 0; t < T_TILES; ++t) {
        const long tb = block0 + (long)t * 64;
        const int xb = t & 1;

        if (t + 1 < T_TILES) issueEV(tb + 64, idxNext);  // flies under L1/epi1
        if (t + 2 < T_TILES) idxNext = load_idx(tb + 128);

        // ---------------- Layer 1 (pure reg + LDS) ----------------
        const unsigned short* Xs = (const unsigned short*)(smem + xb * XBUF_SZ);
        f32x4 acc[2][4];
#pragma unroll
        for (int a = 0; a < 2; ++a)
#pragma unroll
            for (int b = 0; b < 4; ++b)
                acc[a][b] = (f32x4){0.f, 0.f, 0.f, 0.f};

        __builtin_amdgcn_s_setprio(1);
#pragma unroll
        for (int kb = 0; kb < 6; ++kb) {
            short8 bx[4];
#pragma unroll
            for (int mt = 0; mt < 4; ++mt)
                bx[mt] = *reinterpret_cast<const short8*>(
                    &Xs[(mt * 16 + lm) * XPAD + kb * 32 + lg * 8]);
#pragma unroll
            for (int nt = 0; nt < 2; ++nt)
#pragma unroll
                for (int mt = 0; mt < 4; ++mt)
                    acc[nt][mt] = __builtin_amdgcn_mfma_f32_16x16x32_bf16(
                        wA1[kb][nt], bx[mt], acc[nt][mt], 0, 0, 0);
        }
        __builtin_amdgcn_s_setprio(0);

        // epi1: +b1, relu, bf16 -> Hs[xb] (XOR-swizzled)
        unsigned char* Hb = smem + HS_OFF + xb * HBUF_SZ;
#pragma unroll
        for (int nt = 0; nt < 2; ++nt) {
            int n0 = w * 32 + nt * 16 + lg * 4;
            float4 bv = *reinterpret_cast<const float4*>(b1 + n0);
#pragma unroll
            for (int mt = 0; mt < 4; ++mt) {
                f32x4 a = acc[nt][mt];
                ushort4 hb;
                hb.x = f2bf(fmaxf(a[0] + bv.x, 0.f));
                hb.y = f2bf(fmaxf(a[1] + bv.y, 0.f));
                hb.z = f2bf(fmaxf(a[2] + bv.z, 0.f));
                hb.w = f2bf(fmaxf(a[3] + bv.w, 0.f));
                int m = mt * 16 + lm;
                int addr = m * 512 + ((n0 * 2) ^ (lm << 4));
                *reinterpret_cast<ushort4*>(Hb + addr) = hb;
            }
        }

        if (t + 1 < T_TILES) write_lds(xb ^ 1);          // Xs[(t+1)&1]

        BAR_LDS();    // single barrier per tile: Hs[xb] + Xs[xb^1] ready

        // ---------------- Layer 2 (pure reg + LDS) ----------------
#pragma unroll
        for (int a = 0; a < 2; ++a)
#pragma unroll
            for (int b = 0; b < 4; ++b)
                acc[a][b] = (f32x4){0.f, 0.f, 0.f, 0.f};

        __builtin_amdgcn_s_setprio(1);
#pragma unroll
        for (int kb = 0; kb < 8; ++kb) {
            short8 bh[4];
#pragma unroll
            for (int mt = 0; mt < 4; ++mt) {
                int m = mt * 16 + lm;
                int addr = m * 512 + (((kb * 32 + lg * 8) * 2) ^ (lm << 4));
                bh[mt] = *reinterpret_cast<const short8*>(Hb + addr);
            }
#pragma unroll
            for (int ot = 0; ot < 2; ++ot)
#pragma unroll
                for (int mt = 0; mt < 4; ++mt)
                    acc[ot][mt] = __builtin_amdgcn_mfma_f32_16x16x32_bf16(
                        wA2[kb][ot], bh[mt], acc[ot][mt], 0, 0, 0);
        }
        __builtin_amdgcn_s_setprio(0);

        // epi2: +b2, coalesced NT float4 store (never waited in-loop)
#pragma unroll
        for (int ot = 0; ot < 2; ++ot) {
            int o0 = w * 32 + ot * 16 + lg * 4;
            float4 bv = *reinterpret_cast<const float4*>(b2 + o0);
#pragma unroll
            for (int mt = 0; mt < 4; ++mt) {
                f32x4 a = acc[ot][mt];
                f32x4 r;
                r[0] = a[0] + bv.x;
                r[1] = a[1] + bv.y;
                r[2] = a[2] + bv.z;
                r[3] = a[3] + bv.w;
                __builtin_nontemporal_store(r, reinterpret_cast<f32x4*>(
                    out + (size_t)(tb + mt * 16 + lm) * HID_C + o0));
            }
        }
    }
}

extern "C" void kernel_launch(void* const* d_in, const int* in_sizes, int n_in,
                              void* d_out, int out_size, void* d_ws, size_t ws_size,
                              hipStream_t stream) {
    const float* E  = (const float*)d_in[0];
    const float* V  = (const float*)d_in[1];
    const int*   ei = (const int*)d_in[2];   // [2][N_EDGES] int32
    const float* W1 = (const float*)d_in[3];
    const float* b1 = (const float*)d_in[4];
    const float* W2 = (const float*)d_in[5];
    const float* b2 = (const float*)d_in[6];
    float* out = (float*)d_out;

    unsigned short* W1T = (unsigned short*)d_ws;                 // 256*192 bf16
    unsigned short* W2T = W1T + IN_DIM_C * HID_C;                // 256*256 bf16

    const int prep_total = IN_DIM_C * HID_C + HID_C * HID_C;     // 114688
    prep_weights_kernel<<<(prep_total + 255) / 256, 256, 0, stream>>>(W1, W2, W1T, W2T);

    const int nblocks = N_EDGES_C / (64 * T_TILES);              // 3125
    edge_mlp_kernel<<<nblocks, 512, 0, stream>>>(
        E, V, ei, ei + N_EDGES_C, W1T, b1, W2T, b2, out);
}